// Round 2
// baseline (265.952 us; speedup 1.0000x reference)
//
#include <hip/hip_runtime.h>

typedef _Float16 f16x8 __attribute__((ext_vector_type(8)));
typedef float    f32x4 __attribute__((ext_vector_type(4)));
typedef unsigned int u32x4 __attribute__((ext_vector_type(4)));

#if __has_builtin(__builtin_amdgcn_exp2f)
#define EXP2F __builtin_amdgcn_exp2f
#else
#define EXP2F exp2f
#endif
#if __has_builtin(__builtin_amdgcn_rcpf)
#define RCPF __builtin_amdgcn_rcpf
#else
#define RCPF(x) (1.0f/(x))
#endif

static __device__ __forceinline__ float tanh_fast(float x) {
    // tanh(x) = 1 - 2/(1+e^{2x});  e^{2x} = 2^(x*2*log2(e)).  Saturates correctly at +-inf.
    float e = EXP2F(x * 2.8853900817779268f);
    float r = RCPF(e + 1.0f);
    return __builtin_fmaf(-2.0f, r, 1.0f);
}

static __device__ __forceinline__ unsigned pkrtz(float a, float b) {
    auto t = __builtin_amdgcn_cvt_pkrtz(a, b);   // __fp16 ext_vector_type(2)
    return __builtin_bit_cast(unsigned, t);
}

// Block = 256 threads = 4 waves, handles 16 batch elements.
// Wave w owns hidden M-tile rows [w*16, w*16+16) of layers 1 and 2.
// Transposed MFMA scheme: D[m=hidden][n=batch]; lane: c = lane&15 (batch col),
// g = lane>>4.  A-frag: row = lane&15, k = g*8+j (j consecutive).  B-frag:
// col = lane&15, k = g*8+j.  D-frag: col = lane&15, row = g*4+reg.
extern "C" __global__ __launch_bounds__(256, 2)
void rk4_kernel(const float* __restrict__ gu,  const float* __restrict__ gx0,
                const float* __restrict__ gW1, const float* __restrict__ gb1,
                const float* __restrict__ gW2, const float* __restrict__ gb2,
                const float* __restrict__ gW3, const float* __restrict__ gb3,
                const float* __restrict__ gxm, const float* __restrict__ gxs,
                const float* __restrict__ gum, const float* __restrict__ gus,
                float* __restrict__ gout)
{
    constexpr int T = 128;
    const int tid  = threadIdx.x;
    const int lane = tid & 63;
    const int w    = tid >> 6;      // wave id in block = hidden M-tile
    const int c    = lane & 15;     // batch column
    const int g    = lane >> 4;     // k-group
    const int batch = blockIdx.x * 16 + c;

    // [buf][batch col][hidden] f16, rows padded 64->72 (144B) to spread banks.
    __shared__ __align__(16) _Float16 hb[2][16][72];

    // ---- weight fragments (one-time gather; tiny matrices, cache-resident) ----
    f16x8 aW1;   // W1^T rows w*16+c, k = z-dim (0..3 real, rest zero-pad)
#pragma unroll
    for (int j = 0; j < 8; ++j)
        aW1[j] = (_Float16)((g == 0 && j < 4) ? gW1[j * 64 + w * 16 + c] : 0.0f);

    f16x8 aW2[2], aW3[2];
#pragma unroll
    for (int kt = 0; kt < 2; ++kt) {
#pragma unroll
        for (int j = 0; j < 8; ++j) {
            int k = kt * 32 + g * 8 + j;                       // hidden-in
            aW2[kt][j] = (_Float16)gW2[k * 64 + w * 16 + c];   // W2^T[m=w*16+c][k]
            aW3[kt][j] = (_Float16)((c < 3) ? gW3[k * 3 + c] : 0.0f); // W3^T[m=c][k]
        }
    }

    f32x4 bb1, bb2;   // bias for D rows: hidden = w*16 + g*4 + r
#pragma unroll
    for (int r = 0; r < 4; ++r) {
        bb1[r] = gb1[w * 16 + g * 4 + r];
        bb2[r] = gb2[w * 16 + g * 4 + r];
    }

    const float b30 = gb3[0], b31 = gb3[1], b32 = gb3[2];
    const float xm0 = gxm[0], xm1 = gxm[1], xm2 = gxm[2];
    const float xs0 = gxs[0], xs1 = gxs[1], xs2 = gxs[2];
    const float um  = gum[0], us  = gus[0];
    const float ig0 = 1.0f / (5.0f * xs0);   // TAU = 5
    const float ig1 = 1.0f / (5.0f * xs1);
    const float ig2 = 1.0f / (5.0f * xs2);

    float x0v = gx0[batch * 3 + 0];
    float x1v = gx0[batch * 3 + 1];
    float x2v = gx0[batch * 3 + 2];

    const f32x4 zero = {0.0f, 0.0f, 0.0f, 0.0f};

    auto feval = [&](float e0, float e1, float e2, float ue,
                     float& o0, float& o1, float& o2) {
        // Z^T B-frag: k=0..3 -> (x0,x1,x2,u) on g==0 lanes only, else zero.
        unsigned z01 = 0u, z23 = 0u;
        if (g == 0) { z01 = pkrtz(e0, e1); z23 = pkrtz(e2, ue); }
        u32x4 zi = {z01, z23, 0u, 0u};
        f16x8 zb = __builtin_bit_cast(f16x8, zi);

        // L1: H1^T tile w = W1^T @ Z^T
        f32x4 d1 = __builtin_amdgcn_mfma_f32_16x16x32_f16(aW1, zb, zero, 0, 0, 0);
        float h0 = tanh_fast(d1[0] + bb1[0]);
        float h1 = tanh_fast(d1[1] + bb1[1]);
        float h2 = tanh_fast(d1[2] + bb1[2]);
        float h3 = tanh_fast(d1[3] + bb1[3]);
        unsigned long long pa = (unsigned long long)pkrtz(h0, h1)
                              | ((unsigned long long)pkrtz(h2, h3) << 32);
        *(unsigned long long*)&hb[0][c][w * 16 + g * 4] = pa;
        __syncthreads();
        f16x8 hA0 = *(const f16x8*)&hb[0][c][g * 8];        // k = 0..31 slice
        f16x8 hA1 = *(const f16x8*)&hb[0][c][32 + g * 8];   // k = 32..63 slice

        // L2: H2^T tile w = W2^T @ H1^T  (K=64 via 2 MFMAs)
        f32x4 d2 = __builtin_amdgcn_mfma_f32_16x16x32_f16(aW2[0], hA0, zero, 0, 0, 0);
        d2 = __builtin_amdgcn_mfma_f32_16x16x32_f16(aW2[1], hA1, d2, 0, 0, 0);
        float q0 = tanh_fast(d2[0] + bb2[0]);
        float q1 = tanh_fast(d2[1] + bb2[1]);
        float q2 = tanh_fast(d2[2] + bb2[2]);
        float q3 = tanh_fast(d2[3] + bb2[3]);
        unsigned long long pb = (unsigned long long)pkrtz(q0, q1)
                              | ((unsigned long long)pkrtz(q2, q3) << 32);
        *(unsigned long long*)&hb[1][c][w * 16 + g * 4] = pb;
        __syncthreads();
        f16x8 hB0 = *(const f16x8*)&hb[1][c][g * 8];
        f16x8 hB1 = *(const f16x8*)&hb[1][c][32 + g * 8];

        // L3: Xdot^T = W3^T @ H2^T ; rows 0..2 land in g==0 lanes, regs 0..2.
        f32x4 d3 = __builtin_amdgcn_mfma_f32_16x16x32_f16(aW3[0], hB0, zero, 0, 0, 0);
        d3 = __builtin_amdgcn_mfma_f32_16x16x32_f16(aW3[1], hB1, d3, 0, 0, 0);

        // greybox (f32, meaningful on g==0 lanes; bounded elsewhere, unused)
        float xp0 = e0 * xs0 + xm0;
        float xp1 = e1 * xs1 + xm1;
        float xp2 = e2 * xs2 + xm2;
        float up  = ue * us + um;
        o0 = (up - xp0) * ig0 + d3[0] + b30;
        o1 = -xp1 * ig1 + d3[1] + b31;
        o2 = -xp2 * ig2 + d3[2] + b32;
    };

    float ucur = gu[batch * T];
    float* orow = gout + (size_t)batch * (3 * T);

    for (int t = 0; t < T; ++t) {
        if (w == 0 && g == 0) {          // ys[t] = pre-step state (t=0 -> exact x0)
            orow[t * 3 + 0] = x0v;
            orow[t * 3 + 1] = x1v;
            orow[t * 3 + 2] = x2v;
        }
        float unext = gu[batch * T + ((t + 1 < T) ? t + 1 : t)];  // prefetch

        float a0, a1, a2, b0, b1v, b2v, c0, c1, c2, d0, d1v, d2v;
        feval(x0v, x1v, x2v, ucur, a0, a1, a2);
        feval(x0v + 0.5f * a0, x1v + 0.5f * a1, x2v + 0.5f * a2, ucur, b0, b1v, b2v);
        feval(x0v + 0.5f * b0, x1v + 0.5f * b1v, x2v + 0.5f * b2v, ucur, c0, c1, c2);
        feval(x0v + c0, x1v + c1, x2v + c2, ucur, d0, d1v, d2v);

        x0v += (1.0f / 6.0f) * (a0 + 2.0f * b0 + 2.0f * c0 + d0);
        x1v += (1.0f / 6.0f) * (a1 + 2.0f * b1v + 2.0f * c1 + d1v);
        x2v += (1.0f / 6.0f) * (a2 + 2.0f * b2v + 2.0f * c2 + d2v);
        ucur = unext;
    }
}

extern "C" void kernel_launch(void* const* d_in, const int* in_sizes, int n_in,
                              void* d_out, int out_size, void* d_ws, size_t ws_size,
                              hipStream_t stream) {
    const float* u  = (const float*)d_in[0];
    const float* x0 = (const float*)d_in[1];
    const float* W1 = (const float*)d_in[2];
    const float* b1 = (const float*)d_in[3];
    const float* W2 = (const float*)d_in[4];
    const float* b2 = (const float*)d_in[5];
    const float* W3 = (const float*)d_in[6];
    const float* b3 = (const float*)d_in[7];
    const float* xm = (const float*)d_in[8];
    const float* xs = (const float*)d_in[9];
    const float* um = (const float*)d_in[10];
    const float* us = (const float*)d_in[11];
    // 8192 batch / 16 per block = 512 blocks x 256 threads (4 waves, H-split)
    rk4_kernel<<<512, 256, 0, stream>>>(u, x0, W1, b1, W2, b2, W3, b3,
                                        xm, xs, um, us, (float*)d_out);
}

// Round 3
// 237.098 us; speedup vs baseline: 1.1217x; 1.1217x over previous
//
#include <hip/hip_runtime.h>

typedef _Float16 f16x8 __attribute__((ext_vector_type(8)));
typedef float    f32x4 __attribute__((ext_vector_type(4)));
typedef unsigned int u32x4 __attribute__((ext_vector_type(4)));

#if __has_builtin(__builtin_amdgcn_exp2f)
#define EXP2F __builtin_amdgcn_exp2f
#else
#define EXP2F exp2f
#endif
#if __has_builtin(__builtin_amdgcn_rcpf)
#define RCPF __builtin_amdgcn_rcpf
#else
#define RCPF(x) (1.0f/(x))
#endif

static __device__ __forceinline__ float tanh_fast(float x) {
    // tanh(x) = 1 - 2/(1+e^{2x}); e^{2x} = 2^(x*2*log2(e)). Saturates at +-inf.
    float e = EXP2F(x * 2.8853900817779268f);
    float r = RCPF(e + 1.0f);
    return __builtin_fmaf(-2.0f, r, 1.0f);
}

static __device__ __forceinline__ unsigned pkrtz(float a, float b) {
    auto t = __builtin_amdgcn_cvt_pkrtz(a, b);   // __fp16 ext_vector_type(2)
    return __builtin_bit_cast(unsigned, t);
}

// Block = 256 threads = 4 waves, 16 batch columns.
// Wave w owns hidden M-tile rows [w*16, w*16+16) of layers 1,2.
// MFMA 16x16x32 f16, transposed scheme: D[m=hidden][n=batch].
// lane: c = lane&15 (batch col), g = lane>>4.
// A-frag: row = lane&15, k = g*8+j.  B-frag: col = lane&15, k = g*8+j.
// C/D-frag: col = lane&15, row = g*4+reg.
// Biases live in the MFMA C-operand; greybox reduces to o_r = d3[r] - 0.2*e_r
// with all constant terms (b3, xmean terms, per-step u term) folded into L3's C.
extern "C" __global__ __launch_bounds__(256, 2)
void rk4_kernel(const float* __restrict__ gu,  const float* __restrict__ gx0,
                const float* __restrict__ gW1, const float* __restrict__ gb1,
                const float* __restrict__ gW2, const float* __restrict__ gb2,
                const float* __restrict__ gW3, const float* __restrict__ gb3,
                const float* __restrict__ gxm, const float* __restrict__ gxs,
                const float* __restrict__ gum, const float* __restrict__ gus,
                float* __restrict__ gout)
{
    constexpr int T = 128;
    const int tid  = threadIdx.x;
    const int lane = tid & 63;
    const int w    = tid >> 6;
    const int c    = lane & 15;
    const int g    = lane >> 4;
    const int batch = blockIdx.x * 16 + c;

    // [buf][batch col][hidden] f16, rows padded 64->72 halves (144B).
    __shared__ __align__(16) _Float16 hb[2][16][72];

    // ---- weight fragments (one-time gather; tiny, cache-resident) ----
    f16x8 aW1;
#pragma unroll
    for (int j = 0; j < 8; ++j)
        aW1[j] = (_Float16)((g == 0 && j < 4) ? gW1[j * 64 + w * 16 + c] : 0.0f);

    f16x8 aW2[2], aW3[2];
#pragma unroll
    for (int kt = 0; kt < 2; ++kt) {
#pragma unroll
        for (int j = 0; j < 8; ++j) {
            int k = kt * 32 + g * 8 + j;
            aW2[kt][j] = (_Float16)gW2[k * 64 + w * 16 + c];
            aW3[kt][j] = (_Float16)((c < 3) ? gW3[k * 3 + c] : 0.0f);
        }
    }

    f32x4 cb1, cb2;   // bias C-frags: row = w*16 + g*4 + r
#pragma unroll
    for (int r = 0; r < 4; ++r) {
        cb1[r] = gb1[w * 16 + g * 4 + r];
        cb2[r] = gb2[w * 16 + g * 4 + r];
    }

    // Greybox constants.  xstd*ig = 1/TAU exactly => o_r = d3[r] - 0.2*e_r + const.
    const float xs0 = gxs[0], xs1 = gxs[1], xs2 = gxs[2];
    const float ig0 = 1.0f / (5.0f * xs0);
    const float ig1 = 1.0f / (5.0f * xs1);
    const float ig2 = 1.0f / (5.0f * xs2);
    const float ku  = gus[0] * ig0;                       // u coefficient (row 0 only)
    // constant parts incl. b3 (rows 0..2), valid on g==0 lanes only
    f32x4 cgb_base;
    cgb_base[0] = (g == 0) ? (gb3[0] + (gum[0] - gxm[0]) * ig0) : 0.0f;
    cgb_base[1] = (g == 0) ? (gb3[1] - gxm[1] * ig1) : 0.0f;
    cgb_base[2] = (g == 0) ? (gb3[2] - gxm[2] * ig2) : 0.0f;
    cgb_base[3] = 0.0f;

    float x0v = gx0[batch * 3 + 0];
    float x1v = gx0[batch * 3 + 1];
    float x2v = gx0[batch * 3 + 2];

    f32x4 cgb = cgb_base;   // per-step: cgb[0] = base + u-term (g==0 lanes)

    auto feval = [&](float e0, float e1, float e2, float ue,
                     float& o0, float& o1, float& o2) {
        // Z^T B-frag: k=0..3 -> (x0,x1,x2,u) on g==0 lanes only, else zero.
        unsigned z01 = 0u, z23 = 0u;
        if (g == 0) { z01 = pkrtz(e0, e1); z23 = pkrtz(e2, ue); }
        u32x4 zi = {z01, z23, 0u, 0u};
        f16x8 zb = __builtin_bit_cast(f16x8, zi);

        // L1: H1^T tile w = W1^T @ Z^T + b1 (bias via C)
        f32x4 d1 = __builtin_amdgcn_mfma_f32_16x16x32_f16(aW1, zb, cb1, 0, 0, 0);
        float h0 = tanh_fast(d1[0]);
        float h1 = tanh_fast(d1[1]);
        float h2 = tanh_fast(d1[2]);
        float h3 = tanh_fast(d1[3]);
        unsigned long long pa = (unsigned long long)pkrtz(h0, h1)
                              | ((unsigned long long)pkrtz(h2, h3) << 32);
        *(unsigned long long*)&hb[0][c][w * 16 + g * 4] = pa;
        __syncthreads();
        f16x8 hA0 = *(const f16x8*)&hb[0][c][g * 8];
        f16x8 hA1 = *(const f16x8*)&hb[0][c][32 + g * 8];

        // L2: H2^T = W2^T @ H1^T + b2 (K=64 via 2 MFMAs, bias via C of first)
        f32x4 d2 = __builtin_amdgcn_mfma_f32_16x16x32_f16(aW2[0], hA0, cb2, 0, 0, 0);
        d2 = __builtin_amdgcn_mfma_f32_16x16x32_f16(aW2[1], hA1, d2, 0, 0, 0);
        float q0 = tanh_fast(d2[0]);
        float q1 = tanh_fast(d2[1]);
        float q2 = tanh_fast(d2[2]);
        float q3 = tanh_fast(d2[3]);
        unsigned long long pb = (unsigned long long)pkrtz(q0, q1)
                              | ((unsigned long long)pkrtz(q2, q3) << 32);
        *(unsigned long long*)&hb[1][c][w * 16 + g * 4] = pb;
        __syncthreads();
        f16x8 hB0 = *(const f16x8*)&hb[1][c][g * 8];
        f16x8 hB1 = *(const f16x8*)&hb[1][c][32 + g * 8];

        // L3: Xdot^T = W3^T @ H2^T + (b3 + greybox consts + u-term) via C.
        f32x4 d3 = __builtin_amdgcn_mfma_f32_16x16x32_f16(aW3[0], hB0, cgb, 0, 0, 0);
        d3 = __builtin_amdgcn_mfma_f32_16x16x32_f16(aW3[1], hB1, d3, 0, 0, 0);

        // remaining greybox: -e_r/TAU (valid on g==0 lanes, bounded elsewhere)
        o0 = __builtin_fmaf(-0.2f, e0, d3[0]);
        o1 = __builtin_fmaf(-0.2f, e1, d3[1]);
        o2 = __builtin_fmaf(-0.2f, e2, d3[2]);
    };

    float ucur = gu[batch * T];
    float* orow = gout + (size_t)batch * (3 * T);

    for (int t = 0; t < T; ++t) {
        if (w == 0 && g == 0) {          // ys[t] = pre-step state
            orow[t * 3 + 0] = x0v;
            orow[t * 3 + 1] = x1v;
            orow[t * 3 + 2] = x2v;
        }
        float unext = gu[batch * T + ((t + 1 < T) ? t + 1 : t)];  // prefetch

        // per-step u-dependent constant into L3's C (g==0 lanes only)
        cgb[0] = (g == 0) ? __builtin_fmaf(ucur, ku, cgb_base[0]) : 0.0f;

        float a0, a1, a2, b0, b1v, b2v, c0, c1, c2, d0, d1v, d2v;
        feval(x0v, x1v, x2v, ucur, a0, a1, a2);
        feval(x0v + 0.5f * a0, x1v + 0.5f * a1, x2v + 0.5f * a2, ucur, b0, b1v, b2v);
        feval(x0v + 0.5f * b0, x1v + 0.5f * b1v, x2v + 0.5f * b2v, ucur, c0, c1, c2);
        feval(x0v + c0, x1v + c1, x2v + c2, ucur, d0, d1v, d2v);

        x0v += (1.0f / 6.0f) * (a0 + 2.0f * b0 + 2.0f * c0 + d0);
        x1v += (1.0f / 6.0f) * (a1 + 2.0f * b1v + 2.0f * c1 + d1v);
        x2v += (1.0f / 6.0f) * (a2 + 2.0f * b2v + 2.0f * c2 + d2v);
        ucur = unext;
    }
}

extern "C" void kernel_launch(void* const* d_in, const int* in_sizes, int n_in,
                              void* d_out, int out_size, void* d_ws, size_t ws_size,
                              hipStream_t stream) {
    const float* u  = (const float*)d_in[0];
    const float* x0 = (const float*)d_in[1];
    const float* W1 = (const float*)d_in[2];
    const float* b1 = (const float*)d_in[3];
    const float* W2 = (const float*)d_in[4];
    const float* b2 = (const float*)d_in[5];
    const float* W3 = (const float*)d_in[6];
    const float* b3 = (const float*)d_in[7];
    const float* xm = (const float*)d_in[8];
    const float* xs = (const float*)d_in[9];
    const float* um = (const float*)d_in[10];
    const float* us = (const float*)d_in[11];
    rk4_kernel<<<512, 256, 0, stream>>>(u, x0, W1, b1, W2, b2, W3, b3,
                                        xm, xs, um, us, (float*)d_out);
}